// Round 1
// baseline (182.881 us; speedup 1.0000x reference)
//
#include <hip/hip_runtime.h>

typedef unsigned short u16;
typedef unsigned int u32;

typedef __bf16 bf16x8 __attribute__((ext_vector_type(8)));
typedef float f32x4 __attribute__((ext_vector_type(4)));
typedef u16 u16x4 __attribute__((ext_vector_type(4)));

#define NSAMP 2048
#define KH 3
#define NNBR 16
#define F 128
#define OUT_O 256   // C_OUT * F_OUT
#define QT 384      // KH * F

// LDS row strides in bf16 elements (row pad +8 elems = +16B -> 8-bank spread)
#define ZLD 136
#define ALD 136
#define YLD 392

__device__ __forceinline__ u16 f2bf(float f) {
    union { float f; u32 u; } v; v.f = f;
    u32 r = v.u + 0x7fffu + ((v.u >> 16) & 1u);   // RNE
    return (u16)(r >> 16);
}
__device__ __forceinline__ float bf2f(u16 h) {
    union { u32 u; float f; } v; v.u = ((u32)h) << 16;
    return v.f;
}

__global__ void wprep(const float* __restrict__ W, u16* __restrict__ Wbf) {
    int i = blockIdx.x * 256 + threadIdx.x;
    if (i < OUT_O * QT) Wbf[i] = f2bf(W[i]);
}

__launch_bounds__(512, 2)
__global__ void featkhop(const float* __restrict__ xg,
                         const float* __restrict__ ng,
                         const u16* __restrict__ Wbf,
                         float* __restrict__ out) {
    __shared__ __align__(16) u16 Zs[64 * ZLD];     // 49 used rows (x + 48 nbrs), bf16
    __shared__ __align__(16) u16 Aj[F * ALD];      // adj for one q, bf16
    __shared__ __align__(16) u16 Ys[64 * YLD];     // Y = Z @ adj^T (64 x 384), bf16
    __shared__ __align__(16) float xls[F];
    __shared__ __align__(16) float sls[KH][F];
    __shared__ __align__(16) float cs4[4][F];

    const int i = blockIdx.x;
    const int t = threadIdx.x;
    const int lane = t & 63;
    const int w = t >> 6;        // wave 0..7
    const int lr = lane & 15;
    const int lg = lane >> 4;

    // ---- stage x: fp32 to xls, bf16 to Z row 0 ----
    if (t < F / 4) {
        float4 v = *(const float4*)(xg + (size_t)i * F + t * 4);
        *(float4*)(xls + t * 4) = v;
        u16* p = Zs + 0 * ZLD + t * 4;
        u16x4 z; z[0] = f2bf(v.x); z[1] = f2bf(v.y); z[2] = f2bf(v.z); z[3] = f2bf(v.w);
        *(u16x4*)p = z;
    }
    // ---- stage neighbors: bf16 rows 1..48 ----
    {
        const float* nb = ng + (size_t)i * (KH * NNBR * F);
        for (int j = t; j < KH * NNBR * F / 4; j += 512) {
            float4 v = *(const float4*)(nb + j * 4);
            int fl = j * 4;
            int q = fl >> 11;          // / (16*128)
            int n = (fl >> 7) & 15;
            int b = fl & 127;
            u16* p = Zs + (1 + q * NNBR + n) * ZLD + b;
            u16x4 z; z[0] = f2bf(v.x); z[1] = f2bf(v.y); z[2] = f2bf(v.z); z[3] = f2bf(v.w);
            *(u16x4*)p = z;
        }
    }
    // ---- zero pad rows 49..63 ----
    {
        u32* zp = (u32*)(Zs + 49 * ZLD);
        for (int j = t; j < 15 * ZLD / 2; j += 512) zp[j] = 0u;
    }
    __syncthreads();

    // ---- s[q][b] = sum_n nbr[q][n][b] ----
    if (t < KH * F) {
        int q = t >> 7, b = t & 127;
        float s = 0.f;
        #pragma unroll
        for (int n = 0; n < NNBR; ++n) s += bf2f(Zs[(1 + q * NNBR + n) * ZLD + b]);
        sls[q][b] = s;
    }
    __syncthreads();

    // ---- per-q: build adj, GEMM1 into Y ----
    const int bb = t & 127;
    const int gg = t >> 7;       // 0..3
    const int a0 = gg * 32;

    for (int q = 0; q < KH; ++q) {
        // build u = sgnroot(x_a s_b + x_b s_a), column partial sums
        float uv[32];
        {
            float xb = xls[bb], sb = sls[q][bb];
            float ps = 0.f;
            #pragma unroll
            for (int j = 0; j < 32; ++j) {
                float tv = xls[a0 + j] * sb + xb * sls[q][a0 + j];
                float r = 0.f;
                if (tv != 0.f) r = copysignf(sqrtf(fmaxf(fabsf(tv), 1e-8f)), tv);
                uv[j] = r;
                ps += fabsf(r);
            }
            cs4[gg][bb] = ps;
        }
        __syncthreads();
        // normalize columns, store bf16 adj
        {
            float tot = cs4[0][bb] + cs4[1][bb] + cs4[2][bb] + cs4[3][bb];
            float inv = 1.f / (tot + 1e-7f);
            #pragma unroll
            for (int j = 0; j < 32; ++j)
                Aj[(a0 + j) * ALD + bb] = f2bf(uv[j] * inv);
        }
        __syncthreads();

        // GEMM1: Y[:, q*128 + (w*16..w*16+16)] = Z(64x128) @ adj^T
        f32x4 acc[4];
        {
            f32x4 zf = {0.f, 0.f, 0.f, 0.f};
            #pragma unroll
            for (int mt = 0; mt < 4; ++mt) acc[mt] = zf;
        }
        #pragma unroll
        for (int kk = 0; kk < 4; ++kk) {
            // B frag: B[k=b][n=a] = adj[a][b]; lane: a = w*16+lr, b = kk*32 + lg*8 ..+8
            bf16x8 bf = *(const bf16x8*)(Aj + (w * 16 + lr) * ALD + kk * 32 + lg * 8);
            #pragma unroll
            for (int mt = 0; mt < 4; ++mt) {
                bf16x8 af = *(const bf16x8*)(Zs + (mt * 16 + lr) * ZLD + kk * 32 + lg * 8);
                acc[mt] = __builtin_amdgcn_mfma_f32_16x16x32_bf16(af, bf, acc[mt], 0, 0, 0);
            }
        }
        // D layout: row = lg*4 + r, col = lr  (m89-verified)
        #pragma unroll
        for (int mt = 0; mt < 4; ++mt) {
            #pragma unroll
            for (int r = 0; r < 4; ++r)
                Ys[(mt * 16 + lg * 4 + r) * YLD + q * F + w * 16 + lr] = f2bf(acc[mt][r]);
        }
        __syncthreads();
    }

    // ---- GEMM2: out(64x256) = Y(64x384) @ Wm^T; wave w owns o in [32w, 32w+32) ----
    f32x4 acc2[4][2];
    {
        f32x4 zf = {0.f, 0.f, 0.f, 0.f};
        #pragma unroll
        for (int mt = 0; mt < 4; ++mt) { acc2[mt][0] = zf; acc2[mt][1] = zf; }
    }
    #pragma unroll
    for (int kk = 0; kk < 12; ++kk) {
        bf16x8 bf0 = *(const bf16x8*)(Wbf + (size_t)(w * 32 + lr) * QT + kk * 32 + lg * 8);
        bf16x8 bf1 = *(const bf16x8*)(Wbf + (size_t)(w * 32 + 16 + lr) * QT + kk * 32 + lg * 8);
        #pragma unroll
        for (int mt = 0; mt < 4; ++mt) {
            bf16x8 af = *(const bf16x8*)(Ys + (mt * 16 + lr) * YLD + kk * 32 + lg * 8);
            acc2[mt][0] = __builtin_amdgcn_mfma_f32_16x16x32_bf16(af, bf0, acc2[mt][0], 0, 0, 0);
            acc2[mt][1] = __builtin_amdgcn_mfma_f32_16x16x32_bf16(af, bf1, acc2[mt][1], 0, 0, 0);
        }
    }

    // ---- epilogue: row 0 -> x_out, rows 1..48 -> nbr_out ----
    float* xout = out + (size_t)i * OUT_O;
    float* nout = out + (size_t)NSAMP * OUT_O + (size_t)i * 48 * OUT_O;
    #pragma unroll
    for (int mt = 0; mt < 4; ++mt) {
        #pragma unroll
        for (int r = 0; r < 4; ++r) {
            int v = mt * 16 + lg * 4 + r;
            #pragma unroll
            for (int nn = 0; nn < 2; ++nn) {
                int o = w * 32 + nn * 16 + lr;
                float val = acc2[mt][nn][r];
                if (v == 0) xout[o] = val;
                else if (v <= 48) nout[(size_t)(v - 1) * OUT_O + o] = val;
            }
        }
    }
}

extern "C" void kernel_launch(void* const* d_in, const int* in_sizes, int n_in,
                              void* d_out, int out_size, void* d_ws, size_t ws_size,
                              hipStream_t stream) {
    const float* x   = (const float*)d_in[0];
    const float* nbr = (const float*)d_in[1];
    const float* W   = (const float*)d_in[2];
    u16* Wbf = (u16*)d_ws;   // 256*384 bf16 = 192 KiB
    wprep<<<(OUT_O * QT + 255) / 256, 256, 0, stream>>>(W, Wbf);
    featkhop<<<NSAMP, 512, 0, stream>>>(x, nbr, Wbf, (float*)d_out);
}

// Round 2
// 106.759 us; speedup vs baseline: 1.7130x; 1.7130x over previous
//
#include <hip/hip_runtime.h>

typedef unsigned short u16;
typedef unsigned int u32;
typedef __bf16 bf16;
typedef __bf16 bf16x8 __attribute__((ext_vector_type(8)));
typedef __bf16 bf16x4 __attribute__((ext_vector_type(4)));
typedef float f32x4 __attribute__((ext_vector_type(4)));

#define NSAMP 2048
#define KH 3
#define NNBR 16
#define F 128
#define OUT_O 256   // C_OUT * F_OUT
#define QT 384      // KH * F

// LDS row strides in bf16 elements (+8 elems = +16B pad -> 8-bank row spread)
#define ZLD 136
#define ALD 136
#define YLD 136

__device__ __forceinline__ bf16x4 cvt4(float4 v) {
    bf16x4 h;
    h[0] = (bf16)v.x; h[1] = (bf16)v.y; h[2] = (bf16)v.z; h[3] = (bf16)v.w;
    return h;
}

__global__ void wprep(const float* __restrict__ W, bf16* __restrict__ Wbf) {
    int i = blockIdx.x * 256 + threadIdx.x;
    if (i < OUT_O * QT) Wbf[i] = (bf16)W[i];
}

__launch_bounds__(512, 4)
__global__ void featkhop(const float* __restrict__ xg,
                         const float* __restrict__ ng,
                         const bf16* __restrict__ Wbf,
                         float* __restrict__ out) {
    __shared__ __align__(16) bf16 Zs[64 * ZLD];     // rows: x, 48 nbrs, 15 zero
    __shared__ __align__(16) bf16 Aj[F * ALD];      // adj for current q
    __shared__ __align__(16) bf16 Ys[64 * YLD];     // Y panel for current q
    __shared__ __align__(16) float xls[F];
    __shared__ __align__(16) float sls[KH][F];
    __shared__ __align__(16) float cs4[4][F];

    const int i = blockIdx.x;
    const int t = threadIdx.x;
    const int lane = t & 63;
    const int w = t >> 6;        // wave 0..7
    const int lr = lane & 15;
    const int lg = lane >> 4;

    // ---- stage x: fp32 to xls, bf16 to Z row 0 ----
    if (t < F / 4) {
        float4 v = *(const float4*)(xg + (size_t)i * F + t * 4);
        *(float4*)(xls + t * 4) = v;
        *(bf16x4*)(Zs + 0 * ZLD + t * 4) = cvt4(v);
    }
    // ---- stage neighbors: bf16 rows 1..48 ----
    {
        const float* nb = ng + (size_t)i * (KH * NNBR * F);
        #pragma unroll
        for (int c = 0; c < 3; ++c) {
            int j = c * 512 + t;
            float4 v = *(const float4*)(nb + j * 4);
            int fl = j * 4;
            int row = 1 + (fl >> 7);     // neighbor index 0..47 -> rows 1..48
            int b = fl & 127;
            *(bf16x4*)(Zs + row * ZLD + b) = cvt4(v);
        }
    }
    // ---- zero pad rows 49..63 ----
    {
        u32* zp = (u32*)(Zs + 49 * ZLD);
        for (int j = t; j < 15 * ZLD / 2; j += 512) zp[j] = 0u;
    }
    __syncthreads();

    // ---- s[q][b] = sum_n nbr[q][n][b] ----
    if (t < KH * F) {
        int q = t >> 7, b = t & 127;
        float s = 0.f;
        #pragma unroll
        for (int n = 0; n < NNBR; ++n) s += (float)Zs[(1 + q * NNBR + n) * ZLD + b];
        sls[q][b] = s;
    }
    __syncthreads();

    const int bb = t & 127;
    const int gg = t >> 7;       // 0..3
    const int a0 = gg * 32;

    f32x4 acc2[4][2];
    {
        f32x4 zf = {0.f, 0.f, 0.f, 0.f};
        #pragma unroll
        for (int mt = 0; mt < 4; ++mt) { acc2[mt][0] = zf; acc2[mt][1] = zf; }
    }

    for (int q = 0; q < KH; ++q) {
        // ---- build u = sgnroot(x_a s_b + x_b s_a), column partial sums ----
        float uv[32];
        {
            float xb = xls[bb], sb = sls[q][bb];
            float ps = 0.f;
            #pragma unroll
            for (int j = 0; j < 32; ++j) {
                float tv = xls[a0 + j] * sb + xb * sls[q][a0 + j];
                float r = copysignf(__builtin_amdgcn_sqrtf(fmaxf(fabsf(tv), 1e-8f)), tv);
                r = (tv == 0.f) ? 0.f : r;
                uv[j] = r;
                ps += fabsf(r);
            }
            cs4[gg][bb] = ps;
        }
        __syncthreads();
        // ---- normalize columns, store bf16 adj ----
        {
            float tot = cs4[0][bb] + cs4[1][bb] + cs4[2][bb] + cs4[3][bb];
            float inv = 1.f / (tot + 1e-7f);
            #pragma unroll
            for (int j = 0; j < 32; ++j)
                Aj[(a0 + j) * ALD + bb] = (bf16)(uv[j] * inv);
        }
        __syncthreads();

        // ---- GEMM1: Ys[v, a in w*16..+16] = Z(64x128) @ adj^T ----
        f32x4 acc1[4];
        {
            f32x4 zf = {0.f, 0.f, 0.f, 0.f};
            #pragma unroll
            for (int mt = 0; mt < 4; ++mt) acc1[mt] = zf;
        }
        #pragma unroll
        for (int kk = 0; kk < 4; ++kk) {
            // B frag: B[k=b][n=a] = adj[a][b]; lane: a = w*16+lr, b = kk*32+lg*8..+8
            bf16x8 bf = *(const bf16x8*)(Aj + (w * 16 + lr) * ALD + kk * 32 + lg * 8);
            #pragma unroll
            for (int mt = 0; mt < 4; ++mt) {
                bf16x8 af = *(const bf16x8*)(Zs + (mt * 16 + lr) * ZLD + kk * 32 + lg * 8);
                acc1[mt] = __builtin_amdgcn_mfma_f32_16x16x32_bf16(af, bf, acc1[mt], 0, 0, 0);
            }
        }
        // D layout: row = lg*4 + r, col = lr  (m89-verified)
        #pragma unroll
        for (int mt = 0; mt < 4; ++mt) {
            #pragma unroll
            for (int r = 0; r < 4; ++r)
                Ys[(mt * 16 + lg * 4 + r) * YLD + w * 16 + lr] = (bf16)acc1[mt][r];
        }
        __syncthreads();

        // ---- GEMM2 (q-slice): acc2 += Y_q(64x128) @ Wq^T ----
        #pragma unroll
        for (int kk = 0; kk < 4; ++kk) {
            const bf16* wp = Wbf + (size_t)(w * 32 + lr) * QT + q * F + kk * 32 + lg * 8;
            bf16x8 bf0 = *(const bf16x8*)wp;
            bf16x8 bf1 = *(const bf16x8*)(wp + 16 * QT);
            #pragma unroll
            for (int mt = 0; mt < 4; ++mt) {
                bf16x8 af = *(const bf16x8*)(Ys + (mt * 16 + lr) * YLD + kk * 32 + lg * 8);
                acc2[mt][0] = __builtin_amdgcn_mfma_f32_16x16x32_bf16(af, bf0, acc2[mt][0], 0, 0, 0);
                acc2[mt][1] = __builtin_amdgcn_mfma_f32_16x16x32_bf16(af, bf1, acc2[mt][1], 0, 0, 0);
            }
        }
        __syncthreads();
    }

    // ---- epilogue: row 0 -> x_out, rows 1..48 -> nbr_out ----
    float* xout = out + (size_t)i * OUT_O;
    float* nout = out + (size_t)NSAMP * OUT_O + (size_t)i * 48 * OUT_O;
    #pragma unroll
    for (int mt = 0; mt < 4; ++mt) {
        #pragma unroll
        for (int r = 0; r < 4; ++r) {
            int v = mt * 16 + lg * 4 + r;
            #pragma unroll
            for (int nn = 0; nn < 2; ++nn) {
                int o = w * 32 + nn * 16 + lr;
                float val = acc2[mt][nn][r];
                if (v == 0) xout[o] = val;
                else if (v <= 48) nout[(size_t)(v - 1) * OUT_O + o] = val;
            }
        }
    }
}

extern "C" void kernel_launch(void* const* d_in, const int* in_sizes, int n_in,
                              void* d_out, int out_size, void* d_ws, size_t ws_size,
                              hipStream_t stream) {
    const float* x   = (const float*)d_in[0];
    const float* nbr = (const float*)d_in[1];
    const float* W   = (const float*)d_in[2];
    bf16* Wbf = (bf16*)d_ws;   // 256*384 bf16 = 192 KiB
    wprep<<<(OUT_O * QT + 255) / 256, 256, 0, stream>>>(W, Wbf);
    featkhop<<<NSAMP, 512, 0, stream>>>(x, nbr, Wbf, (float*)d_out);
}

// Round 3
// 86.531 us; speedup vs baseline: 2.1135x; 1.2338x over previous
//
#include <hip/hip_runtime.h>

typedef unsigned short u16;
typedef unsigned int u32;
typedef __bf16 bf16;
typedef __bf16 bf16x8 __attribute__((ext_vector_type(8)));
typedef __bf16 bf16x4 __attribute__((ext_vector_type(4)));
typedef float f32x4 __attribute__((ext_vector_type(4)));

#define NSAMP 2048
#define KH 3
#define NNBR 16
#define F 128
#define OUT_O 256   // C_OUT * F_OUT
#define QT 384      // KH * F

// LDS row strides in bf16 elements (+8 elems = +16B pad -> 8-bank row spread)
#define ZLD 136
#define YLD 136

__device__ __forceinline__ bf16x4 cvt4(float4 v) {
    bf16x4 h;
    h[0] = (bf16)v.x; h[1] = (bf16)v.y; h[2] = (bf16)v.z; h[3] = (bf16)v.w;
    return h;
}

__global__ void wprep(const float* __restrict__ W, bf16* __restrict__ Wbf) {
    int i = blockIdx.x * 256 + threadIdx.x;
    if (i < OUT_O * QT) Wbf[i] = (bf16)W[i];
}

__launch_bounds__(512, 4)
__global__ void featkhop(const float* __restrict__ xg,
                         const float* __restrict__ ng,
                         const bf16* __restrict__ Wbf,
                         float* __restrict__ out) {
    __shared__ __align__(16) bf16 Zs[64 * ZLD];       // rows: x, 48 nbrs (49-63 unused)
    __shared__ __align__(16) bf16 Ys[2][64 * YLD];    // double-buffered Y panel
    __shared__ __align__(16) float xls[F];
    __shared__ __align__(16) float sls[KH][F];
    __shared__ __align__(16) float rs[F];             // per-q colsum (=rowsum) of |u|

    const int i = blockIdx.x;
    const int t = threadIdx.x;
    const int lane = t & 63;
    const int w = t >> 6;        // wave 0..7
    const int lr = lane & 15;
    const int lg = lane >> 4;

    // ---- stage x: fp32 to xls, bf16 to Z row 0 ----
    if (t < F / 4) {
        float4 v = *(const float4*)(xg + (size_t)i * F + t * 4);
        *(float4*)(xls + t * 4) = v;
        *(bf16x4*)(Zs + 0 * ZLD + t * 4) = cvt4(v);
    }
    // ---- stage neighbors: bf16 rows 1..48 ----
    {
        const float* nb = ng + (size_t)i * (KH * NNBR * F);
        #pragma unroll
        for (int c = 0; c < 3; ++c) {
            int j = c * 512 + t;
            float4 v = *(const float4*)(nb + j * 4);
            int fl = j * 4;
            int row = 1 + (fl >> 7);     // neighbor 0..47 -> rows 1..48
            int b = fl & 127;
            *(bf16x4*)(Zs + row * ZLD + b) = cvt4(v);
        }
    }
    __syncthreads();

    // ---- s[q][b] = sum_n nbr[q][n][b] ----
    if (t < KH * F) {
        int q = t >> 7, b = t & 127;
        float s = 0.f;
        #pragma unroll
        for (int n = 0; n < NNBR; ++n) s += (float)Zs[(1 + q * NNBR + n) * ZLD + b];
        sls[q][b] = s;
    }
    __syncthreads();

    const int a_row = w * 16 + lr;          // adjacency row this lane owns
    const float x_a = xls[a_row];
    const int cbase = lg * 8;               // within-32 col offset

    f32x4 acc2[4][2];
    {
        f32x4 zf = {0.f, 0.f, 0.f, 0.f};
        #pragma unroll
        for (int mt = 0; mt < 4; ++mt) { acc2[mt][0] = zf; acc2[mt][1] = zf; }
    }

    for (int q = 0; q < KH; ++q) {
        const float s_a = sls[q][a_row];
        // ---- build u-row fragment in registers: uv[kk*8+e] = sgnroot at (a_row, b) ----
        float uv[32];
        float ps = 0.f;
        #pragma unroll
        for (int kk = 0; kk < 4; ++kk) {
            float4 xb0 = *(const float4*)(xls + kk * 32 + cbase);
            float4 xb1 = *(const float4*)(xls + kk * 32 + cbase + 4);
            float4 sb0 = *(const float4*)(sls[q] + kk * 32 + cbase);
            float4 sb1 = *(const float4*)(sls[q] + kk * 32 + cbase + 4);
            float xb[8] = {xb0.x, xb0.y, xb0.z, xb0.w, xb1.x, xb1.y, xb1.z, xb1.w};
            float sb[8] = {sb0.x, sb0.y, sb0.z, sb0.w, sb1.x, sb1.y, sb1.z, sb1.w};
            #pragma unroll
            for (int e = 0; e < 8; ++e) {
                float tv = x_a * sb[e] + xb[e] * s_a;
                float r = tv * __builtin_amdgcn_rsqf(fmaxf(fabsf(tv), 1e-8f));
                uv[kk * 8 + e] = r;
                ps += fabsf(r);
            }
        }
        // rowsum[a] over all 128 b: reduce across the 4 lg-mates (lane bits 4,5)
        ps += __shfl_xor(ps, 16);
        ps += __shfl_xor(ps, 32);
        if (lg == 0) rs[a_row] = ps;        // rowsum == colsum by symmetry
        __syncthreads();                     // A

        // ---- normalize into bf16 B-fragments ----
        bf16x8 bfrag[4];
        #pragma unroll
        for (int kk = 0; kk < 4; ++kk) {
            float4 r0 = *(const float4*)(rs + kk * 32 + cbase);
            float4 r1 = *(const float4*)(rs + kk * 32 + cbase + 4);
            float rr[8] = {r0.x, r0.y, r0.z, r0.w, r1.x, r1.y, r1.z, r1.w};
            #pragma unroll
            for (int e = 0; e < 8; ++e)
                bfrag[kk][e] = (bf16)(uv[kk * 8 + e] * __builtin_amdgcn_rcpf(rr[e] + 1e-7f));
        }

        // ---- GEMM1: Ys[q&1][v, a in w*16..+16] = Z(64x128) @ adj^T ----
        bf16* Ysb = Ys[q & 1];
        f32x4 acc1[4];
        {
            f32x4 zf = {0.f, 0.f, 0.f, 0.f};
            #pragma unroll
            for (int mt = 0; mt < 4; ++mt) acc1[mt] = zf;
        }
        #pragma unroll
        for (int kk = 0; kk < 4; ++kk) {
            #pragma unroll
            for (int mt = 0; mt < 4; ++mt) {
                bf16x8 af = *(const bf16x8*)(Zs + (mt * 16 + lr) * ZLD + kk * 32 + cbase);
                acc1[mt] = __builtin_amdgcn_mfma_f32_16x16x32_bf16(af, bfrag[kk], acc1[mt], 0, 0, 0);
            }
        }
        // D layout: row = lg*4 + r, col = lr
        #pragma unroll
        for (int mt = 0; mt < 4; ++mt) {
            #pragma unroll
            for (int r = 0; r < 4; ++r)
                Ysb[(mt * 16 + lg * 4 + r) * YLD + w * 16 + lr] = (bf16)acc1[mt][r];
        }
        __syncthreads();                     // B

        // ---- GEMM2 (q-slice): acc2 += Y_q(64x128) @ Wq^T ----
        #pragma unroll
        for (int kk = 0; kk < 4; ++kk) {
            const bf16* wp = Wbf + (size_t)(w * 32 + lr) * QT + q * F + kk * 32 + cbase;
            bf16x8 bf0 = *(const bf16x8*)wp;
            bf16x8 bf1 = *(const bf16x8*)(wp + 16 * QT);
            #pragma unroll
            for (int mt = 0; mt < 4; ++mt) {
                bf16x8 af = *(const bf16x8*)(Ysb + (mt * 16 + lr) * YLD + kk * 32 + cbase);
                acc2[mt][0] = __builtin_amdgcn_mfma_f32_16x16x32_bf16(af, bf0, acc2[mt][0], 0, 0, 0);
                acc2[mt][1] = __builtin_amdgcn_mfma_f32_16x16x32_bf16(af, bf1, acc2[mt][1], 0, 0, 0);
            }
        }
        // no trailing barrier: next q writes the other Ys buffer; rs rewrite is
        // separated from this q's rs reads by barrier B(q) + A(q+1).
    }

    // ---- epilogue: row 0 -> x_out, rows 1..48 -> nbr_out ----
    float* xout = out + (size_t)i * OUT_O;
    float* nout = out + (size_t)NSAMP * OUT_O + (size_t)i * 48 * OUT_O;
    #pragma unroll
    for (int mt = 0; mt < 4; ++mt) {
        #pragma unroll
        for (int r = 0; r < 4; ++r) {
            int v = mt * 16 + lg * 4 + r;
            #pragma unroll
            for (int nn = 0; nn < 2; ++nn) {
                int o = w * 32 + nn * 16 + lr;
                float val = acc2[mt][nn][r];
                if (v == 0) xout[o] = val;
                else if (v <= 48) nout[(size_t)(v - 1) * OUT_O + o] = val;
            }
        }
    }
}

extern "C" void kernel_launch(void* const* d_in, const int* in_sizes, int n_in,
                              void* d_out, int out_size, void* d_ws, size_t ws_size,
                              hipStream_t stream) {
    const float* x   = (const float*)d_in[0];
    const float* nbr = (const float*)d_in[1];
    const float* W   = (const float*)d_in[2];
    bf16* Wbf = (bf16*)d_ws;   // 256*384 bf16 = 192 KiB
    wprep<<<(OUT_O * QT + 255) / 256, 256, 0, stream>>>(W, Wbf);
    featkhop<<<NSAMP, 512, 0, stream>>>(x, nbr, Wbf, (float*)d_out);
}